// Round 7
// baseline (385.203 us; speedup 1.0000x reference)
//
#include <hip/hip_runtime.h>

#define T 32
#define C 2048
#define NTOT 600
#define NCLASS 20
#define NSUP 5
#define PER 30
#define NQPC 25
#define NQ 500
#define NQROWS (NQ * T)      // 16000
#define NPROWS (NCLASS * T)  // 640
#define GAMMA 0.1f
#define INVG 10.0f
#define BIG 1e10f
#define NMM (NQ * NCLASS + NQ + NCLASS)  // 10520
#define HALF_NMM (NMM / 2)               // 5260
#define GEMM_BLKS 625
#define SYRK_BLKS_PAD 136  // multiple of 8 so gemm swizzle sees o%8 unchanged
#define STAGE_BLKS_A 2000  // (16000/16 rows) x 2 halves
#define STAGE_BLKS_B 80    // (640/16) x 2

typedef __fp16 half8 __attribute__((ext_vector_type(8)));
typedef float f32x4 __attribute__((ext_vector_type(4)));

__device__ __forceinline__ void gload16(const void* g, void* l) {
    __builtin_amdgcn_global_load_lds((const __attribute__((address_space(1))) void*)g,
                                     (__attribute__((address_space(3))) void*)l, 16, 0, 0);
}

// ---------------- parallel stable counting sort (1 block) ----------------
__global__ __launch_bounds__(640) void sort_kernel(const int* __restrict__ target,
                                                   int* __restrict__ order,
                                                   int* __restrict__ qsrc) {
    __shared__ int tgt[NTOT];
    __shared__ int offs[NCLASS];
    __shared__ int ordl[NTOT];
    int tid = threadIdx.x;
    if (tid < NTOT) tgt[tid] = target[tid];
    __syncthreads();
    if (tid < NCLASS) {
        int o = 0;
        for (int i = 0; i < NTOT; i++) o += (tgt[i] < tid) ? 1 : 0;
        offs[tid] = o;
    }
    __syncthreads();
    if (tid < NTOT) {
        int c = tgt[tid];
        int rank = 0;
        for (int k = 0; k < NTOT; k++) rank += (k < tid && tgt[k] == c) ? 1 : 0;
        ordl[offs[c] + rank] = tid;
    }
    __syncthreads();
    if (tid < NTOT) order[tid] = ordl[tid];
    if (tid < NQ) qsrc[tid] = ordl[(tid / NQPC) * PER + NSUP + (tid % NQPC)];
}

// ---------------- streaming staging: gather/mean + f16 split ----------------
// A side: hi only (f16 rounding of query rows). B side: hi + lo (proto to ~22 bits).
// Layout: CHUNK-MAJOR dst[chunk*nrows + row] (half8 = cols chunk*8..+8).
__global__ __launch_bounds__(512) void stage_kernel(const float* __restrict__ inp,
                                                    const int* __restrict__ qsrc,
                                                    const int* __restrict__ order,
                                                    half8* __restrict__ Ah,
                                                    half8* __restrict__ Bh,
                                                    half8* __restrict__ Bl) {
    int bid = blockIdx.x;
    int tid = threadIdx.x;
    int row = tid & 15, seg = tid >> 4;  // seg 0..31
    bool isA = bid < STAGE_BLKS_A;
    int b = isA ? bid : bid - STAGE_BLKS_A;
    int rowblk = b >> 1, half = b & 1;
    int rowg = rowblk * 16 + row;
    int col0 = half * 1024 + seg * 32;
    float vals[32];
    if (isA) {
        const float* src = inp + (size_t)qsrc[rowg >> 5] * (T * C) + (size_t)(rowg & 31) * C + col0;
#pragma unroll
        for (int i = 0; i < 8; i++) {
            float4 v = *(const float4*)(src + i * 4);
            vals[i * 4 + 0] = v.x; vals[i * 4 + 1] = v.y;
            vals[i * 4 + 2] = v.z; vals[i * 4 + 3] = v.w;
        }
        half8 hv[4];
#pragma unroll
        for (int e = 0; e < 32; e++) hv[e >> 3][e & 7] = (__fp16)vals[e];
        int chunk0 = half * 128 + seg * 4;
#pragma unroll
        for (int c = 0; c < 4; c++) Ah[(size_t)(chunk0 + c) * NQROWS + rowg] = hv[c];
    } else {
        int cls = rowg >> 5, trow = rowg & 31;
        const float* base = inp + (size_t)trow * C + col0;
        const float* s0 = base + (size_t)order[cls * PER + 0] * (T * C);
        const float* s1 = base + (size_t)order[cls * PER + 1] * (T * C);
        const float* s2 = base + (size_t)order[cls * PER + 2] * (T * C);
        const float* s3 = base + (size_t)order[cls * PER + 3] * (T * C);
        const float* s4 = base + (size_t)order[cls * PER + 4] * (T * C);
#pragma unroll
        for (int i = 0; i < 8; i++) {
            float4 a = *(const float4*)(s0 + i * 4);
            float4 b4 = *(const float4*)(s1 + i * 4);
            float4 c = *(const float4*)(s2 + i * 4);
            float4 d = *(const float4*)(s3 + i * 4);
            float4 e = *(const float4*)(s4 + i * 4);
            vals[i * 4 + 0] = (a.x + b4.x + c.x + d.x + e.x) * 0.2f;
            vals[i * 4 + 1] = (a.y + b4.y + c.y + d.y + e.y) * 0.2f;
            vals[i * 4 + 2] = (a.z + b4.z + c.z + d.z + e.z) * 0.2f;
            vals[i * 4 + 3] = (a.w + b4.w + c.w + d.w + e.w) * 0.2f;
        }
        half8 hv[4], lv[4];
#pragma unroll
        for (int e = 0; e < 32; e++) {
            float f = vals[e];
            __fp16 h = (__fp16)f;
            hv[e >> 3][e & 7] = h;
            lv[e >> 3][e & 7] = (__fp16)(f - (float)h);
        }
        int chunk0 = half * 128 + seg * 4;
#pragma unroll
        for (int c = 0; c < 4; c++) {
            size_t o = (size_t)(chunk0 + c) * NPROWS + rowg;
            Bh[o] = hv[c];
            Bl[o] = lv[c];
        }
    }
}

// ---------------- merged: SYRK (blocks 0..135) + f16 2-term MFMA GEMM ----------------
__global__ __launch_bounds__(256) void gemm_syrk_kernel(const half8* __restrict__ Ah,
                                                        const half8* __restrict__ Bh,
                                                        const half8* __restrict__ Bl,
                                                        float* __restrict__ xy,
                                                        float* __restrict__ gxx,
                                                        float* __restrict__ gyy) {
    __shared__ half8 sAh[512], sBh[512], sBl[512];  // 24 KB
    int tid = threadIdx.x, lane = tid & 63, wid = tid >> 6;
    int o = blockIdx.x;
    if (o < SYRK_BLKS_PAD) {
        // ---- SYRK path: one wave per 32x32 Gram matrix (short blocks first) ----
        int ww = o * 4 + wid;
        if (ww >= NQ + NCLASS) return;
        int r = lane & 15, g = lane >> 4;
        f32x4 acc[2][2];
        f32x4 zero = {0.f, 0.f, 0.f, 0.f};
        acc[0][0] = zero; acc[0][1] = zero; acc[1][0] = zero; acc[1][1] = zero;
        float* outp;
        if (ww < NQ) {
            // gxx = Ah Ah^T  (1-term: self-consistent with 2-term xy)
            int row0 = ww * 32;
            outp = gxx + (size_t)ww * (T * T);
            for (int t = 0; t < C / 32; t++) {
                size_t base = (size_t)(t * 4 + g) * NQROWS + row0 + r;
                half8 h0 = Ah[base], h1 = Ah[base + 16];
                acc[0][0] = __builtin_amdgcn_mfma_f32_16x16x32_f16(h0, h0, acc[0][0], 0, 0, 0);
                acc[0][1] = __builtin_amdgcn_mfma_f32_16x16x32_f16(h0, h1, acc[0][1], 0, 0, 0);
                acc[1][0] = __builtin_amdgcn_mfma_f32_16x16x32_f16(h1, h0, acc[1][0], 0, 0, 0);
                acc[1][1] = __builtin_amdgcn_mfma_f32_16x16x32_f16(h1, h1, acc[1][1], 0, 0, 0);
            }
        } else {
            // gyy = (Bh+Bl)(Bh+Bl)^T, 3-term
            int row0 = (ww - NQ) * 32;
            outp = gyy + (size_t)(ww - NQ) * (T * T);
            for (int t = 0; t < C / 32; t++) {
                size_t base = (size_t)(t * 4 + g) * NPROWS + row0 + r;
                half8 h0 = Bh[base], h1 = Bh[base + 16];
                half8 l0 = Bl[base], l1 = Bl[base + 16];
                acc[0][0] = __builtin_amdgcn_mfma_f32_16x16x32_f16(h0, h0, acc[0][0], 0, 0, 0);
                acc[0][0] = __builtin_amdgcn_mfma_f32_16x16x32_f16(h0, l0, acc[0][0], 0, 0, 0);
                acc[0][0] = __builtin_amdgcn_mfma_f32_16x16x32_f16(l0, h0, acc[0][0], 0, 0, 0);
                acc[0][1] = __builtin_amdgcn_mfma_f32_16x16x32_f16(h0, h1, acc[0][1], 0, 0, 0);
                acc[0][1] = __builtin_amdgcn_mfma_f32_16x16x32_f16(h0, l1, acc[0][1], 0, 0, 0);
                acc[0][1] = __builtin_amdgcn_mfma_f32_16x16x32_f16(l0, h1, acc[0][1], 0, 0, 0);
                acc[1][0] = __builtin_amdgcn_mfma_f32_16x16x32_f16(h1, h0, acc[1][0], 0, 0, 0);
                acc[1][0] = __builtin_amdgcn_mfma_f32_16x16x32_f16(h1, l0, acc[1][0], 0, 0, 0);
                acc[1][0] = __builtin_amdgcn_mfma_f32_16x16x32_f16(l1, h0, acc[1][0], 0, 0, 0);
                acc[1][1] = __builtin_amdgcn_mfma_f32_16x16x32_f16(h1, h1, acc[1][1], 0, 0, 0);
                acc[1][1] = __builtin_amdgcn_mfma_f32_16x16x32_f16(h1, l1, acc[1][1], 0, 0, 0);
                acc[1][1] = __builtin_amdgcn_mfma_f32_16x16x32_f16(l1, h1, acc[1][1], 0, 0, 0);
            }
        }
#pragma unroll
        for (int mi = 0; mi < 2; mi++)
#pragma unroll
            for (int ni = 0; ni < 2; ni++)
#pragma unroll
                for (int j = 0; j < 4; j++)
                    outp[(mi * 16 + g * 4 + j) * T + ni * 16 + r] = acc[mi][ni][j];
        return;
    }
    // ---- GEMM path: xy = Ah*(Bh+Bl)^T, 2 MFMA terms ----
    int oo = o - SYRK_BLKS_PAD;  // 0..624; SYRK_BLKS_PAD%8==0 keeps oo%8==o%8
    int xcd = oo & 7, slot = oo >> 3;
    int v = (xcd < 1 ? xcd * 79 : 79 + (xcd - 1) * 78) + slot;  // bijective over 625=8*78+1
    int bm = v / 5, bn = v % 5;
    int wr = wid >> 1, wc = wid & 1;
    int m0 = bm * 128, n0 = bn * 128;
    int i0 = tid, i1 = tid + 256;
    const half8* gAh0 = Ah + (size_t)(i0 >> 7) * NQROWS + m0 + (i0 & 127);
    const half8* gAh1 = Ah + (size_t)(i1 >> 7) * NQROWS + m0 + (i1 & 127);
    const half8* gBh0 = Bh + (size_t)(i0 >> 7) * NPROWS + n0 + (i0 & 127);
    const half8* gBh1 = Bh + (size_t)(i1 >> 7) * NPROWS + n0 + (i1 & 127);
    const half8* gBl0 = Bl + (size_t)(i0 >> 7) * NPROWS + n0 + (i0 & 127);
    const half8* gBl1 = Bl + (size_t)(i1 >> 7) * NPROWS + n0 + (i1 & 127);
    f32x4 acc[4][4];
    f32x4 zero = {0.f, 0.f, 0.f, 0.f};
#pragma unroll
    for (int mi = 0; mi < 4; mi++)
#pragma unroll
        for (int ni = 0; ni < 4; ni++) acc[mi][ni] = zero;
    int g = lane >> 4, r = lane & 15;
    int aoff = g * 128 + wr * 64 + r;
    int boff = g * 128 + wc * 64 + r;
    for (int t = 0; t < C / 32; t++) {
        gload16(gAh0, &sAh[i0]); gload16(gAh1, &sAh[i1]);
        gload16(gBh0, &sBh[i0]); gload16(gBh1, &sBh[i1]);
        gload16(gBl0, &sBl[i0]); gload16(gBl1, &sBl[i1]);
        gAh0 += 4 * NQROWS; gAh1 += 4 * NQROWS;
        gBh0 += 4 * NPROWS; gBh1 += 4 * NPROWS;
        gBl0 += 4 * NPROWS; gBl1 += 4 * NPROWS;
        __syncthreads();
        half8 ah[4], bh[4], bl[4];
#pragma unroll
        for (int i = 0; i < 4; i++) {
            ah[i] = sAh[aoff + i * 16];
            bh[i] = sBh[boff + i * 16];
            bl[i] = sBl[boff + i * 16];
        }
#pragma unroll
        for (int mi = 0; mi < 4; mi++)
#pragma unroll
            for (int ni = 0; ni < 4; ni++) {
                acc[mi][ni] = __builtin_amdgcn_mfma_f32_16x16x32_f16(ah[mi], bh[ni], acc[mi][ni], 0, 0, 0);
                acc[mi][ni] = __builtin_amdgcn_mfma_f32_16x16x32_f16(ah[mi], bl[ni], acc[mi][ni], 0, 0, 0);
            }
        __syncthreads();
    }
    int orow = m0 + wr * 64 + (lane >> 4) * 4;
    int ocol = n0 + wc * 64 + (lane & 15);
#pragma unroll
    for (int mi = 0; mi < 4; mi++)
#pragma unroll
        for (int ni = 0; ni < 4; ni++)
#pragma unroll
            for (int j = 0; j < 4; j++)
                xy[(size_t)(orow + mi * 16 + j) * NPROWS + ocol + ni * 16] = acc[mi][ni][j];
}

// ---------------- extract row norms from Gram diagonals ----------------
__global__ void diag_kernel(const float* __restrict__ gxx, const float* __restrict__ gyy,
                            float* __restrict__ x2, float* __restrict__ y2) {
    int i = blockIdx.x * 256 + threadIdx.x;
    if (i < NQROWS) {
        x2[i] = gxx[(size_t)(i >> 5) * (T * T) + (i & 31) * (T + 1)];
    } else if (i < NQROWS + NPROWS) {
        int j = i - NQROWS;
        y2[j] = gyy[(size_t)(j >> 5) * (T * T) + (j & 31) * (T + 1)];
    }
}

// ---------------- soft-DTW DP: TWO 32x32 matrices per thread (ILP) ----------------
__device__ __forceinline__ void dtw_resolve(int mm, const float* xy, const float* gxx,
                                            const float* gyy, const float* x2,
                                            const float* y2, float* dxy, float* dxx,
                                            float* dyy, const float*& rterm,
                                            const float*& cterm, const float*& cptr,
                                            int& cstride, float*& outp) {
    if (mm < NQ * NCLASS) {
        int q = mm / NCLASS, m = mm % NCLASS;
        rterm = x2 + q * T;
        cterm = y2 + m * T;
        cptr = xy + (size_t)(q * T) * NPROWS + m * T;
        cstride = NPROWS;
        outp = dxy + mm;
    } else if (mm < NQ * NCLASS + NQ) {
        int i = mm - NQ * NCLASS;
        rterm = x2 + i * T;
        cterm = rterm;
        cptr = gxx + (size_t)i * (T * T);
        cstride = T;
        outp = dxx + i;
    } else {
        int i = mm - NQ * NCLASS - NQ;
        rterm = y2 + i * T;
        cterm = rterm;
        cptr = gyy + (size_t)i * (T * T);
        cstride = T;
        outp = dyy + i;
    }
}

__global__ void softdtw_all_kernel(const float* __restrict__ xy, const float* __restrict__ gxx,
                                   const float* __restrict__ gyy, const float* __restrict__ x2,
                                   const float* __restrict__ y2, float* __restrict__ dxy,
                                   float* __restrict__ dxx, float* __restrict__ dyy) {
    int idx = blockIdx.x * 64 + threadIdx.x;
    if (idx >= HALF_NMM) return;
    const float *rt0, *ct0, *cp0, *rt1, *ct1, *cp1;
    int cs0, cs1;
    float *op0, *op1;
    dtw_resolve(idx, xy, gxx, gyy, x2, y2, dxy, dxx, dyy, rt0, ct0, cp0, cs0, op0);
    dtw_resolve(idx + HALF_NMM, xy, gxx, gyy, x2, y2, dxy, dxx, dyy, rt1, ct1, cp1, cs1, op1);
    float cj0[T], cj1[T];
#pragma unroll
    for (int j = 0; j < T; j++) { cj0[j] = ct0[j]; cj1[j] = ct1[j]; }
    float Rp0[T + 1], Rp1[T + 1];
    Rp0[0] = 0.f; Rp1[0] = 0.f;
#pragma unroll
    for (int j = 1; j <= T; j++) { Rp0[j] = BIG; Rp1[j] = BIG; }
    for (int i = 0; i < T; i++) {
        float diag0 = Rp0[0], diag1 = Rp1[0];
        Rp0[0] = BIG; Rp1[0] = BIG;
        float left0 = BIG, left1 = BIG;
        float ai0 = rt0[i], ai1 = rt1[i];
        const float4* crow0 = (const float4*)(cp0 + (size_t)i * cs0);
        const float4* crow1 = (const float4*)(cp1 + (size_t)i * cs1);
#pragma unroll
        for (int jj = 0; jj < 8; jj++) {
            float4 va = crow0[jj];
            float4 vb = crow1[jj];
            float ca[4] = {va.x, va.y, va.z, va.w};
            float cb[4] = {vb.x, vb.y, vb.z, vb.w};
#pragma unroll
            for (int e = 0; e < 4; e++) {
                int j = jj * 4 + e;
                float up0 = Rp0[j + 1];
                float up1 = Rp1[j + 1];
                float d0 = ai0 + cj0[j] - 2.0f * ca[e];
                float d1 = ai1 + cj1[j] - 2.0f * cb[e];
                float mn0 = fminf(diag0, fminf(up0, left0));
                float mn1 = fminf(diag1, fminf(up1, left1));
                float s0 = __expf((mn0 - diag0) * INVG) + __expf((mn0 - up0) * INVG) +
                           __expf((mn0 - left0) * INVG);
                float s1 = __expf((mn1 - diag1) * INVG) + __expf((mn1 - up1) * INVG) +
                           __expf((mn1 - left1) * INVG);
                float r0 = d0 + mn0 - GAMMA * __logf(s0);
                float r1 = d1 + mn1 - GAMMA * __logf(s1);
                diag0 = up0; diag1 = up1;
                Rp0[j + 1] = r0; Rp1[j + 1] = r1;
                left0 = r0; left1 = r1;
            }
        }
    }
    *op0 = Rp0[T];
    *op1 = Rp1[T];
}

// ---------------- finalize: dist, log-softmax, loss, acc ----------------
__global__ __launch_bounds__(512) void finalize_kernel(const float* __restrict__ dxy,
                                                       const float* __restrict__ dxx,
                                                       const float* __restrict__ dyy,
                                                       float* __restrict__ out) {
    __shared__ float sl[512];
    __shared__ float sa[512];
    int q = threadIdx.x;
    float bl = 0.f, fl = 0.f;
    if (q < NQ) {
        float dxxq = dxx[q];
        int cq = q / NQPC;
        float dd[NCLASS];
#pragma unroll
        for (int m = 0; m < NCLASS; m++)
            dd[m] = dxy[q * NCLASS + m] - 0.5f * (dxxq + dyy[m]);
        float best = dd[0];
        int bi = 0;
#pragma unroll
        for (int m = 1; m < NCLASS; m++) {
            if (dd[m] < best) { best = dd[m]; bi = m; }
        }
        float s = 0.f;
        float dcq = dd[0];
#pragma unroll
        for (int m = 0; m < NCLASS; m++) {
            s += __expf(best - dd[m]);
            if (m == cq) dcq = dd[m];
        }
        float lse = __logf(s) - best;
        bl = dcq + lse;
        out[2 + q] = bl;
        fl = (bi == cq) ? 1.f : 0.f;
    }
    sl[threadIdx.x] = bl;
    sa[threadIdx.x] = fl;
    __syncthreads();
    for (int off = 256; off; off >>= 1) {
        if (threadIdx.x < off) {
            sl[threadIdx.x] += sl[threadIdx.x + off];
            sa[threadIdx.x] += sa[threadIdx.x + off];
        }
        __syncthreads();
    }
    if (threadIdx.x == 0) {
        out[0] = sl[0] / (float)NQ;
        out[1] = sa[0] / (float)NQ;
    }
}

extern "C" void kernel_launch(void* const* d_in, const int* in_sizes, int n_in,
                              void* d_out, int out_size, void* d_ws, size_t ws_size,
                              hipStream_t stream) {
    const float* inp = (const float*)d_in[0];
    const int* target = (const int*)d_in[1];
    float* out = (float*)d_out;
    char* ws = (char*)d_ws;

    size_t off = 0;
    auto carve = [&](size_t bytes) {
        void* p = ws + off;
        off = (off + bytes + 255) & ~(size_t)255;
        return p;
    };
    int* order = (int*)carve(NTOT * sizeof(int));
    int* qsrc = (int*)carve(NQ * sizeof(int));
    float* x2 = (float*)carve((size_t)NQROWS * sizeof(float));
    float* y2 = (float*)carve((size_t)NPROWS * sizeof(float));
    float* xy = (float*)carve((size_t)NQROWS * NPROWS * sizeof(float));  // 41 MB
    float* gxx = (float*)carve((size_t)NQ * T * T * sizeof(float));
    float* gyy = (float*)carve((size_t)NCLASS * T * T * sizeof(float));
    float* dxy = (float*)carve((size_t)NQ * NCLASS * sizeof(float));
    float* dxx = (float*)carve((size_t)NQ * sizeof(float));
    float* dyy = (float*)carve((size_t)NCLASS * sizeof(float));
    half8* Ah = (half8*)carve((size_t)(C / 8) * NQROWS * 16);  // 65.5 MB chunk-major
    half8* Bh = (half8*)carve((size_t)(C / 8) * NPROWS * 16);  // 2.6 MB
    half8* Bl = (half8*)carve((size_t)(C / 8) * NPROWS * 16);
    (void)ws_size;

    sort_kernel<<<1, 640, 0, stream>>>(target, order, qsrc);
    stage_kernel<<<STAGE_BLKS_A + STAGE_BLKS_B, 512, 0, stream>>>(inp, qsrc, order, Ah, Bh, Bl);
    gemm_syrk_kernel<<<SYRK_BLKS_PAD + GEMM_BLKS, 256, 0, stream>>>(Ah, Bh, Bl, xy, gxx, gyy);
    diag_kernel<<<(NQROWS + NPROWS + 255) / 256, 256, 0, stream>>>(gxx, gyy, x2, y2);
    softdtw_all_kernel<<<(HALF_NMM + 63) / 64, 64, 0, stream>>>(xy, gxx, gyy, x2, y2, dxy, dxx, dyy);
    finalize_kernel<<<1, 512, 0, stream>>>(dxy, dxx, dyy, out);
}

// Round 8
// 276.783 us; speedup vs baseline: 1.3917x; 1.3917x over previous
//
#include <hip/hip_runtime.h>

#define T 32
#define C 2048
#define NTOT 600
#define NCLASS 20
#define NSUP 5
#define PER 30
#define NQPC 25
#define NQ 500
#define NQROWS (NQ * T)      // 16000
#define NPROWS (NCLASS * T)  // 640
#define GAMMA 0.1f
#define INVG 10.0f
#define BIG 1e10f
#define NMM (NQ * NCLASS + NQ + NCLASS)  // 10520
#define GEMM_BLKS 625
#define SYRK_BLKS_PAD 136  // multiple of 8 so gemm swizzle sees o%8 unchanged
#define STAGE_BLKS_A 2000  // (16000/16 rows) x 2 halves
#define STAGE_BLKS_B 80    // (640/16) x 2

typedef __fp16 half8 __attribute__((ext_vector_type(8)));
typedef float f32x4 __attribute__((ext_vector_type(4)));

__device__ __forceinline__ void gload16(const void* g, void* l) {
    __builtin_amdgcn_global_load_lds((const __attribute__((address_space(1))) void*)g,
                                     (__attribute__((address_space(3))) void*)l, 16, 0, 0);
}

// ---------------- parallel stable counting sort (1 block) ----------------
__global__ __launch_bounds__(640) void sort_kernel(const int* __restrict__ target,
                                                   int* __restrict__ order,
                                                   int* __restrict__ qsrc) {
    __shared__ int tgt[NTOT];
    __shared__ int offs[NCLASS];
    __shared__ int ordl[NTOT];
    int tid = threadIdx.x;
    if (tid < NTOT) tgt[tid] = target[tid];
    __syncthreads();
    if (tid < NCLASS) {
        int o = 0;
        for (int i = 0; i < NTOT; i++) o += (tgt[i] < tid) ? 1 : 0;
        offs[tid] = o;
    }
    __syncthreads();
    if (tid < NTOT) {
        int c = tgt[tid];
        int rank = 0;
        for (int k = 0; k < NTOT; k++) rank += (k < tid && tgt[k] == c) ? 1 : 0;
        ordl[offs[c] + rank] = tid;
    }
    __syncthreads();
    if (tid < NTOT) order[tid] = ordl[tid];
    if (tid < NQ) qsrc[tid] = ordl[(tid / NQPC) * PER + NSUP + (tid % NQPC)];
}

// ---------------- streaming staging: gather/mean + f16 split ----------------
// A side: hi only (f16 rounding of query rows). B side: hi + lo (proto to ~22 bits).
// Layout: CHUNK-MAJOR dst[chunk*nrows + row] (half8 = cols chunk*8..+8).
__global__ __launch_bounds__(512) void stage_kernel(const float* __restrict__ inp,
                                                    const int* __restrict__ qsrc,
                                                    const int* __restrict__ order,
                                                    half8* __restrict__ Ah,
                                                    half8* __restrict__ Bh,
                                                    half8* __restrict__ Bl) {
    int bid = blockIdx.x;
    int tid = threadIdx.x;
    int row = tid & 15, seg = tid >> 4;  // seg 0..31
    bool isA = bid < STAGE_BLKS_A;
    int b = isA ? bid : bid - STAGE_BLKS_A;
    int rowblk = b >> 1, half = b & 1;
    int rowg = rowblk * 16 + row;
    int col0 = half * 1024 + seg * 32;
    float vals[32];
    if (isA) {
        const float* src = inp + (size_t)qsrc[rowg >> 5] * (T * C) + (size_t)(rowg & 31) * C + col0;
#pragma unroll
        for (int i = 0; i < 8; i++) {
            float4 v = *(const float4*)(src + i * 4);
            vals[i * 4 + 0] = v.x; vals[i * 4 + 1] = v.y;
            vals[i * 4 + 2] = v.z; vals[i * 4 + 3] = v.w;
        }
        half8 hv[4];
#pragma unroll
        for (int e = 0; e < 32; e++) hv[e >> 3][e & 7] = (__fp16)vals[e];
        int chunk0 = half * 128 + seg * 4;
#pragma unroll
        for (int c = 0; c < 4; c++) Ah[(size_t)(chunk0 + c) * NQROWS + rowg] = hv[c];
    } else {
        int cls = rowg >> 5, trow = rowg & 31;
        const float* base = inp + (size_t)trow * C + col0;
        const float* s0 = base + (size_t)order[cls * PER + 0] * (T * C);
        const float* s1 = base + (size_t)order[cls * PER + 1] * (T * C);
        const float* s2 = base + (size_t)order[cls * PER + 2] * (T * C);
        const float* s3 = base + (size_t)order[cls * PER + 3] * (T * C);
        const float* s4 = base + (size_t)order[cls * PER + 4] * (T * C);
#pragma unroll
        for (int i = 0; i < 8; i++) {
            float4 a = *(const float4*)(s0 + i * 4);
            float4 b4 = *(const float4*)(s1 + i * 4);
            float4 c = *(const float4*)(s2 + i * 4);
            float4 d = *(const float4*)(s3 + i * 4);
            float4 e = *(const float4*)(s4 + i * 4);
            vals[i * 4 + 0] = (a.x + b4.x + c.x + d.x + e.x) * 0.2f;
            vals[i * 4 + 1] = (a.y + b4.y + c.y + d.y + e.y) * 0.2f;
            vals[i * 4 + 2] = (a.z + b4.z + c.z + d.z + e.z) * 0.2f;
            vals[i * 4 + 3] = (a.w + b4.w + c.w + d.w + e.w) * 0.2f;
        }
        half8 hv[4], lv[4];
#pragma unroll
        for (int e = 0; e < 32; e++) {
            float f = vals[e];
            __fp16 h = (__fp16)f;
            hv[e >> 3][e & 7] = h;
            lv[e >> 3][e & 7] = (__fp16)(f - (float)h);
        }
        int chunk0 = half * 128 + seg * 4;
#pragma unroll
        for (int c = 0; c < 4; c++) {
            size_t o = (size_t)(chunk0 + c) * NPROWS + rowg;
            Bh[o] = hv[c];
            Bl[o] = lv[c];
        }
    }
}

// ---------------- merged: SYRK (blocks 0..135) + f16 2-term MFMA GEMM ----------------
__global__ __launch_bounds__(256) void gemm_syrk_kernel(const half8* __restrict__ Ah,
                                                        const half8* __restrict__ Bh,
                                                        const half8* __restrict__ Bl,
                                                        float* __restrict__ xy,
                                                        float* __restrict__ gxx,
                                                        float* __restrict__ gyy) {
    __shared__ half8 sAh[512], sBh[512], sBl[512];  // 24 KB
    int tid = threadIdx.x, lane = tid & 63, wid = tid >> 6;
    int o = blockIdx.x;
    if (o < SYRK_BLKS_PAD) {
        // ---- SYRK path: one wave per 32x32 Gram matrix (short blocks first) ----
        int ww = o * 4 + wid;
        if (ww >= NQ + NCLASS) return;
        int r = lane & 15, g = lane >> 4;
        f32x4 acc[2][2];
        f32x4 zero = {0.f, 0.f, 0.f, 0.f};
        acc[0][0] = zero; acc[0][1] = zero; acc[1][0] = zero; acc[1][1] = zero;
        float* outp;
        if (ww < NQ) {
            // gxx = Ah Ah^T  (1-term: self-consistent with 2-term xy)
            int row0 = ww * 32;
            outp = gxx + (size_t)ww * (T * T);
            for (int t = 0; t < C / 32; t++) {
                size_t base = (size_t)(t * 4 + g) * NQROWS + row0 + r;
                half8 h0 = Ah[base], h1 = Ah[base + 16];
                acc[0][0] = __builtin_amdgcn_mfma_f32_16x16x32_f16(h0, h0, acc[0][0], 0, 0, 0);
                acc[0][1] = __builtin_amdgcn_mfma_f32_16x16x32_f16(h0, h1, acc[0][1], 0, 0, 0);
                acc[1][0] = __builtin_amdgcn_mfma_f32_16x16x32_f16(h1, h0, acc[1][0], 0, 0, 0);
                acc[1][1] = __builtin_amdgcn_mfma_f32_16x16x32_f16(h1, h1, acc[1][1], 0, 0, 0);
            }
        } else {
            // gyy = (Bh+Bl)(Bh+Bl)^T, 3-term
            int row0 = (ww - NQ) * 32;
            outp = gyy + (size_t)(ww - NQ) * (T * T);
            for (int t = 0; t < C / 32; t++) {
                size_t base = (size_t)(t * 4 + g) * NPROWS + row0 + r;
                half8 h0 = Bh[base], h1 = Bh[base + 16];
                half8 l0 = Bl[base], l1 = Bl[base + 16];
                acc[0][0] = __builtin_amdgcn_mfma_f32_16x16x32_f16(h0, h0, acc[0][0], 0, 0, 0);
                acc[0][0] = __builtin_amdgcn_mfma_f32_16x16x32_f16(h0, l0, acc[0][0], 0, 0, 0);
                acc[0][0] = __builtin_amdgcn_mfma_f32_16x16x32_f16(l0, h0, acc[0][0], 0, 0, 0);
                acc[0][1] = __builtin_amdgcn_mfma_f32_16x16x32_f16(h0, h1, acc[0][1], 0, 0, 0);
                acc[0][1] = __builtin_amdgcn_mfma_f32_16x16x32_f16(h0, l1, acc[0][1], 0, 0, 0);
                acc[0][1] = __builtin_amdgcn_mfma_f32_16x16x32_f16(l0, h1, acc[0][1], 0, 0, 0);
                acc[1][0] = __builtin_amdgcn_mfma_f32_16x16x32_f16(h1, h0, acc[1][0], 0, 0, 0);
                acc[1][0] = __builtin_amdgcn_mfma_f32_16x16x32_f16(h1, l0, acc[1][0], 0, 0, 0);
                acc[1][0] = __builtin_amdgcn_mfma_f32_16x16x32_f16(l1, h0, acc[1][0], 0, 0, 0);
                acc[1][1] = __builtin_amdgcn_mfma_f32_16x16x32_f16(h1, h1, acc[1][1], 0, 0, 0);
                acc[1][1] = __builtin_amdgcn_mfma_f32_16x16x32_f16(h1, l1, acc[1][1], 0, 0, 0);
                acc[1][1] = __builtin_amdgcn_mfma_f32_16x16x32_f16(l1, h1, acc[1][1], 0, 0, 0);
            }
        }
#pragma unroll
        for (int mi = 0; mi < 2; mi++)
#pragma unroll
            for (int ni = 0; ni < 2; ni++)
#pragma unroll
                for (int j = 0; j < 4; j++)
                    outp[(mi * 16 + g * 4 + j) * T + ni * 16 + r] = acc[mi][ni][j];
        return;
    }
    // ---- GEMM path: xy = Ah*(Bh+Bl)^T, 2 MFMA terms ----
    int oo = o - SYRK_BLKS_PAD;  // 0..624; SYRK_BLKS_PAD%8==0 keeps oo%8==o%8
    int xcd = oo & 7, slot = oo >> 3;
    int v = (xcd < 1 ? xcd * 79 : 79 + (xcd - 1) * 78) + slot;  // bijective over 625=8*78+1
    int bm = v / 5, bn = v % 5;
    int wr = wid >> 1, wc = wid & 1;
    int m0 = bm * 128, n0 = bn * 128;
    int i0 = tid, i1 = tid + 256;
    const half8* gAh0 = Ah + (size_t)(i0 >> 7) * NQROWS + m0 + (i0 & 127);
    const half8* gAh1 = Ah + (size_t)(i1 >> 7) * NQROWS + m0 + (i1 & 127);
    const half8* gBh0 = Bh + (size_t)(i0 >> 7) * NPROWS + n0 + (i0 & 127);
    const half8* gBh1 = Bh + (size_t)(i1 >> 7) * NPROWS + n0 + (i1 & 127);
    const half8* gBl0 = Bl + (size_t)(i0 >> 7) * NPROWS + n0 + (i0 & 127);
    const half8* gBl1 = Bl + (size_t)(i1 >> 7) * NPROWS + n0 + (i1 & 127);
    f32x4 acc[4][4];
    f32x4 zero = {0.f, 0.f, 0.f, 0.f};
#pragma unroll
    for (int mi = 0; mi < 4; mi++)
#pragma unroll
        for (int ni = 0; ni < 4; ni++) acc[mi][ni] = zero;
    int g = lane >> 4, r = lane & 15;
    int aoff = g * 128 + wr * 64 + r;
    int boff = g * 128 + wc * 64 + r;
    for (int t = 0; t < C / 32; t++) {
        gload16(gAh0, &sAh[i0]); gload16(gAh1, &sAh[i1]);
        gload16(gBh0, &sBh[i0]); gload16(gBh1, &sBh[i1]);
        gload16(gBl0, &sBl[i0]); gload16(gBl1, &sBl[i1]);
        gAh0 += 4 * NQROWS; gAh1 += 4 * NQROWS;
        gBh0 += 4 * NPROWS; gBh1 += 4 * NPROWS;
        gBl0 += 4 * NPROWS; gBl1 += 4 * NPROWS;
        __syncthreads();
        half8 ah[4], bh[4], bl[4];
#pragma unroll
        for (int i = 0; i < 4; i++) {
            ah[i] = sAh[aoff + i * 16];
            bh[i] = sBh[boff + i * 16];
            bl[i] = sBl[boff + i * 16];
        }
#pragma unroll
        for (int mi = 0; mi < 4; mi++)
#pragma unroll
            for (int ni = 0; ni < 4; ni++) {
                acc[mi][ni] = __builtin_amdgcn_mfma_f32_16x16x32_f16(ah[mi], bh[ni], acc[mi][ni], 0, 0, 0);
                acc[mi][ni] = __builtin_amdgcn_mfma_f32_16x16x32_f16(ah[mi], bl[ni], acc[mi][ni], 0, 0, 0);
            }
        __syncthreads();
    }
    int orow = m0 + wr * 64 + (lane >> 4) * 4;
    int ocol = n0 + wc * 64 + (lane & 15);
#pragma unroll
    for (int mi = 0; mi < 4; mi++)
#pragma unroll
        for (int ni = 0; ni < 4; ni++)
#pragma unroll
            for (int j = 0; j < 4; j++)
                xy[(size_t)(orow + mi * 16 + j) * NPROWS + ocol + ni * 16] = acc[mi][ni][j];
}

// ---------------- extract row norms from Gram diagonals ----------------
__global__ void diag_kernel(const float* __restrict__ gxx, const float* __restrict__ gyy,
                            float* __restrict__ x2, float* __restrict__ y2) {
    int i = blockIdx.x * 256 + threadIdx.x;
    if (i < NQROWS) {
        x2[i] = gxx[(size_t)(i >> 5) * (T * T) + (i & 31) * (T + 1)];
    } else if (i < NQROWS + NPROWS) {
        int j = i - NQROWS;
        y2[j] = gyy[(size_t)(j >> 5) * (T * T) + (j & 31) * (T + 1)];
    }
}

// ---------------- soft-DTW DP: one thread per 32x32 cost matrix ----------------
__global__ __launch_bounds__(64) void softdtw_all_kernel(
        const float* __restrict__ xy, const float* __restrict__ gxx,
        const float* __restrict__ gyy, const float* __restrict__ x2,
        const float* __restrict__ y2, float* __restrict__ dxy,
        float* __restrict__ dxx, float* __restrict__ dyy) {
    int mm = blockIdx.x * 64 + threadIdx.x;
    if (mm >= NMM) return;
    const float* rterm;
    const float* cterm;
    const float* cptr;
    int cstride;
    float* outp;
    if (mm < NQ * NCLASS) {
        int q = mm / NCLASS, m = mm % NCLASS;
        rterm = x2 + q * T;
        cterm = y2 + m * T;
        cptr = xy + (size_t)(q * T) * NPROWS + m * T;
        cstride = NPROWS;
        outp = dxy + mm;
    } else if (mm < NQ * NCLASS + NQ) {
        int i = mm - NQ * NCLASS;
        rterm = x2 + i * T;
        cterm = rterm;
        cptr = gxx + (size_t)i * (T * T);
        cstride = T;
        outp = dxx + i;
    } else {
        int i = mm - NQ * NCLASS - NQ;
        rterm = y2 + i * T;
        cterm = rterm;
        cptr = gyy + (size_t)i * (T * T);
        cstride = T;
        outp = dyy + i;
    }
    float cj[T];
#pragma unroll
    for (int j = 0; j < T; j++) cj[j] = cterm[j];
    float Rp[T + 1];
    Rp[0] = 0.f;
#pragma unroll
    for (int j = 1; j <= T; j++) Rp[j] = BIG;
    for (int i = 0; i < T; i++) {
        float diag = Rp[0];
        Rp[0] = BIG;
        float left = BIG;
        float ai = rterm[i];
        const float4* crow4 = (const float4*)(cptr + (size_t)i * cstride);
        float cr[T];
#pragma unroll
        for (int jj = 0; jj < 8; jj++) {
            float4 v = crow4[jj];
            cr[jj * 4 + 0] = v.x; cr[jj * 4 + 1] = v.y;
            cr[jj * 4 + 2] = v.z; cr[jj * 4 + 3] = v.w;
        }
#pragma unroll
        for (int j = 0; j < T; j++) {
            float up = Rp[j + 1];
            float d = ai + cj[j] - 2.0f * cr[j];
            float mn = fminf(diag, fminf(up, left));
            float ssum = __expf((mn - diag) * INVG) + __expf((mn - up) * INVG) +
                         __expf((mn - left) * INVG);
            float rr = d + mn - GAMMA * __logf(ssum);
            diag = up;
            Rp[j + 1] = rr;
            left = rr;
        }
    }
    *outp = Rp[T];
}

// ---------------- finalize: dist, log-softmax, loss, acc ----------------
__global__ __launch_bounds__(512) void finalize_kernel(const float* __restrict__ dxy,
                                                       const float* __restrict__ dxx,
                                                       const float* __restrict__ dyy,
                                                       float* __restrict__ out) {
    __shared__ float sl[512];
    __shared__ float sa[512];
    int q = threadIdx.x;
    float bl = 0.f, fl = 0.f;
    if (q < NQ) {
        float dxxq = dxx[q];
        int cq = q / NQPC;
        float dd[NCLASS];
#pragma unroll
        for (int m = 0; m < NCLASS; m++)
            dd[m] = dxy[q * NCLASS + m] - 0.5f * (dxxq + dyy[m]);
        float best = dd[0];
        int bi = 0;
#pragma unroll
        for (int m = 1; m < NCLASS; m++) {
            if (dd[m] < best) { best = dd[m]; bi = m; }
        }
        float s = 0.f;
        float dcq = dd[0];
#pragma unroll
        for (int m = 0; m < NCLASS; m++) {
            s += __expf(best - dd[m]);
            if (m == cq) dcq = dd[m];
        }
        float lse = __logf(s) - best;
        bl = dcq + lse;
        out[2 + q] = bl;
        fl = (bi == cq) ? 1.f : 0.f;
    }
    sl[threadIdx.x] = bl;
    sa[threadIdx.x] = fl;
    __syncthreads();
    for (int off = 256; off; off >>= 1) {
        if (threadIdx.x < off) {
            sl[threadIdx.x] += sl[threadIdx.x + off];
            sa[threadIdx.x] += sa[threadIdx.x + off];
        }
        __syncthreads();
    }
    if (threadIdx.x == 0) {
        out[0] = sl[0] / (float)NQ;
        out[1] = sa[0] / (float)NQ;
    }
}

extern "C" void kernel_launch(void* const* d_in, const int* in_sizes, int n_in,
                              void* d_out, int out_size, void* d_ws, size_t ws_size,
                              hipStream_t stream) {
    const float* inp = (const float*)d_in[0];
    const int* target = (const int*)d_in[1];
    float* out = (float*)d_out;
    char* ws = (char*)d_ws;

    size_t off = 0;
    auto carve = [&](size_t bytes) {
        void* p = ws + off;
        off = (off + bytes + 255) & ~(size_t)255;
        return p;
    };
    int* order = (int*)carve(NTOT * sizeof(int));
    int* qsrc = (int*)carve(NQ * sizeof(int));
    float* x2 = (float*)carve((size_t)NQROWS * sizeof(float));
    float* y2 = (float*)carve((size_t)NPROWS * sizeof(float));
    float* xy = (float*)carve((size_t)NQROWS * NPROWS * sizeof(float));  // 41 MB
    float* gxx = (float*)carve((size_t)NQ * T * T * sizeof(float));
    float* gyy = (float*)carve((size_t)NCLASS * T * T * sizeof(float));
    float* dxy = (float*)carve((size_t)NQ * NCLASS * sizeof(float));
    float* dxx = (float*)carve((size_t)NQ * sizeof(float));
    float* dyy = (float*)carve((size_t)NCLASS * sizeof(float));
    half8* Ah = (half8*)carve((size_t)(C / 8) * NQROWS * 16);  // 65.5 MB chunk-major
    half8* Bh = (half8*)carve((size_t)(C / 8) * NPROWS * 16);  // 2.6 MB
    half8* Bl = (half8*)carve((size_t)(C / 8) * NPROWS * 16);
    (void)ws_size;

    sort_kernel<<<1, 640, 0, stream>>>(target, order, qsrc);
    stage_kernel<<<STAGE_BLKS_A + STAGE_BLKS_B, 512, 0, stream>>>(inp, qsrc, order, Ah, Bh, Bl);
    gemm_syrk_kernel<<<SYRK_BLKS_PAD + GEMM_BLKS, 256, 0, stream>>>(Ah, Bh, Bl, xy, gxx, gyy);
    diag_kernel<<<(NQROWS + NPROWS + 255) / 256, 256, 0, stream>>>(gxx, gyy, x2, y2);
    softdtw_all_kernel<<<(NMM + 63) / 64, 64, 0, stream>>>(xy, gxx, gyy, x2, y2, dxy, dxx, dyy);
    finalize_kernel<<<1, 512, 0, stream>>>(dxy, dxx, dyy, out);
}